// Round 11
// baseline (459.205 us; speedup 1.0000x reference)
//
#include <hip/hip_runtime.h>
#include <hip/hip_bf16.h>

#define GN 50000
#define GE 800000
#define GH 4
#define GFH 32
#define GC 40
#define GIN 128

typedef __hip_bfloat16 bf16;
typedef __attribute__((ext_vector_type(8))) short bf16x8;
typedef __attribute__((ext_vector_type(4))) float f32x4;

// mode m: 0 = tensor stored as bf16, 1 = stored as fp32
static __device__ __forceinline__ float ldx(const void* p, size_t i, int m) {
    if (m) return ((const float*)p)[i];
    return __bfloat162float(((const bf16*)p)[i]);
}
static __device__ __forceinline__ void stx(void* p, size_t i, int m, float v) {
    if (m) ((float*)p)[i] = v;
    else ((bf16*)p)[i] = __float2bfloat16(v);
}
static __device__ __forceinline__ unsigned short f2bfu(float v) {
    union { bf16 b; unsigned short u; } cv;
    cv.b = __float2bfloat16(v);
    return cv.u;
}
static __device__ __forceinline__ float lo16(unsigned u) { return __uint_as_float(u << 16); }
static __device__ __forceinline__ float hi16(unsigned u) { return __uint_as_float(u & 0xFFFF0000u); }
static __device__ __forceinline__ float guard_finite(float v) {
    if (!(v == v) || fabsf(v) > 1e30f) return 0.f;
    return v;
}

// ---------------- dtype probe: fp32 misread as bf16 shows wild exponents ----------------
__global__ void detect_kernel(const unsigned short* __restrict__ f, int* __restrict__ flag) {
    int t = threadIdx.x;  // 256
    unsigned short u = f[t];
    int e = (u >> 7) & 0xFF;
    if (e >= 0x8E) atomicAdd(flag, 1);  // |val| >= 2^15 or inf/nan -> not sane bf16 data
}

__global__ void sentinel_kernel(unsigned short* __restrict__ o, int n) {
    int i = blockIdx.x * blockDim.x + threadIdx.x;
    if (i < n) o[i] = 0x3F80;  // bf16 1.0
}

// ---------------- CSR build (simple path; bucketed variant was not faster) ----------------
__global__ void count_kernel(const int* __restrict__ dst, int* __restrict__ deg, int n) {
    int e = blockIdx.x * blockDim.x + threadIdx.x;
    if (e < n) {
        int d = dst[e];
        if (d >= 0 && d < GN) atomicAdd(&deg[d], 1);
    }
}

// ---- 3-pass device-wide scan (indptr / cursor) ----
__global__ void scan1_kernel(const int* __restrict__ deg, int* __restrict__ tmp,
                             int* __restrict__ bsum, int n) {
    int tid = threadIdx.x;
    int i = blockIdx.x * 256 + tid;
    int v = (i < n) ? deg[i] : 0;
    int lane = tid & 63, wid = tid >> 6;
    int s = v;
#pragma unroll
    for (int off = 1; off < 64; off <<= 1) {
        int u = __shfl_up(s, off);
        if (lane >= off) s += u;
    }
    __shared__ int wsum[4];
    if (lane == 63) wsum[wid] = s;
    __syncthreads();
    int woff = 0;
#pragma unroll
    for (int w = 0; w < 4; w++) woff += (w < wid) ? wsum[w] : 0;
    int incl = s + woff;
    if (i < n) tmp[i] = incl;
    if (tid == 255) bsum[blockIdx.x] = incl;  // block total (zeros padded past n)
}

__global__ void scan2_kernel(int* __restrict__ bsum, int nb) {
    int tid = threadIdx.x;
    int v = (tid < nb) ? bsum[tid] : 0;
    int lane = tid & 63, wid = tid >> 6;
    int s = v;
#pragma unroll
    for (int off = 1; off < 64; off <<= 1) {
        int u = __shfl_up(s, off);
        if (lane >= off) s += u;
    }
    __shared__ int wsum[4];
    if (lane == 63) wsum[wid] = s;
    __syncthreads();
    int woff = 0;
#pragma unroll
    for (int w = 0; w < 4; w++) woff += (w < wid) ? wsum[w] : 0;
    if (tid < nb) bsum[tid] = s + woff - v;  // exclusive
}

__global__ void scan3_kernel(const int* __restrict__ deg, const int* __restrict__ tmp,
                             const int* __restrict__ bsum, int* __restrict__ indptr,
                             int* __restrict__ cursor, int n) {
    int i = blockIdx.x * 256 + threadIdx.x;
    if (i < n) {
        int incl = tmp[i] + bsum[blockIdx.x];
        indptr[i + 1] = incl;
        cursor[i] = incl - deg[i];
        if (i == 0) indptr[0] = 0;
    }
}

__global__ void scatter_kernel(const int* __restrict__ src, const int* __restrict__ dst,
                               int* __restrict__ cursor, int* __restrict__ csr_src, int n) {
    int e = blockIdx.x * blockDim.x + threadIdx.x;
    if (e < n) {
        int d = dst[e];
        if (d < 0 || d >= GN) return;
        int p = atomicAdd(&cursor[d], 1);
        if (p >= 0 && p < GE) csr_src[p] = src[e];
    }
}

// ---------------- all weight transposes + wmean in ONE dispatch ----------------
// WT[c][128] = bf16(W[k][c]); tf2 rows 160..207 = wmt (head-mean of w_lin2, zero-pad >=40)
__global__ void wtrans_all(const void* __restrict__ wf0, const void* __restrict__ wl0,
                           const void* __restrict__ wf1, const void* __restrict__ wl1,
                           const void* __restrict__ wf2, const void* __restrict__ wl2,
                           unsigned short* __restrict__ tf0, unsigned short* __restrict__ tl0,
                           unsigned short* __restrict__ tf1, unsigned short* __restrict__ tl1,
                           unsigned short* __restrict__ tf2, const int* __restrict__ flag) {
    int m = (*flag != 0) ? 1 : 0;
    int idx = blockIdx.x * blockDim.x + threadIdx.x;
    if (idx < 4 * 16384) {
        int which = idx >> 14, local = idx & 16383;
        const void* w = (which == 0) ? wf0 : (which == 1) ? wl0 : (which == 2) ? wf1 : wl1;
        unsigned short* t = (which == 0) ? tf0 : (which == 1) ? tl0 : (which == 2) ? tf1 : tl1;
        int c = local & 127, k = local >> 7;
        t[(size_t)c * 128 + k] = f2bfu(ldx(w, (size_t)k * 128 + c, m));
    } else if (idx < 4 * 16384 + 160 * 128) {
        int local = idx - 4 * 16384;
        int c = local % 160, k = local / 160;
        tf2[(size_t)c * 128 + k] = f2bfu(ldx(wf2, (size_t)k * 160 + c, m));
    } else if (idx < 4 * 16384 + 160 * 128 + 48 * 128) {
        int local = idx - 4 * 16384 - 160 * 128;
        int c = local >> 7, k = local & 127;
        float s = 0.f;
        if (c < 40) {
            s = 0.25f * (ldx(wl2, (size_t)k * 160 + c, m) + ldx(wl2, (size_t)k * 160 + 40 + c, m) +
                         ldx(wl2, (size_t)k * 160 + 80 + c, m) +
                         ldx(wl2, (size_t)k * 160 + 120 + c, m));
        }
        tf2[(size_t)(160 + c) * 128 + k] = f2bfu(s);
    }
}

// ---------------- BN coefficients: y = relu(x*ka[c] + kb[c]) ----------------
__global__ void bn_coef(const float* __restrict__ gsum, const float* __restrict__ gsq,
                        const void* __restrict__ g, const void* __restrict__ be,
                        float* __restrict__ ka, float* __restrict__ kb, int n,
                        const int* __restrict__ flag) {
    int c = threadIdx.x;  // 128
    int m = (*flag != 0) ? 1 : 0;
    float inv_n = 1.f / (float)n;
    float mu = gsum[c] * inv_n;
    float var = gsq[c] * inv_n - mu * mu;
    float k = rsqrtf(fmaxf(var, 0.f) + 1e-5f) * ldx(g, c, m);
    ka[c] = k;
    kb[c] = ldx(be, c, m) - mu * k;
}

// BN+ReLU transform of a uint4 (8 bf16 cols starting at k0)
static __device__ __forceinline__ uint4 bnx8(uint4 v, int k0, const float* __restrict__ ka,
                                             const float* __restrict__ kb) {
    unsigned* pw = (unsigned*)&v;
#pragma unroll
    for (int j = 0; j < 4; j++) {
        int c = k0 + 2 * j;
        float y0 = fmaf(lo16(pw[j]), ka[c], kb[c]);
        float y1 = fmaf(hi16(pw[j]), ka[c + 1], kb[c + 1]);
        y0 = y0 > 0.f ? y0 : 0.f;
        y1 = y1 > 0.f ? y1 : 0.f;
        pw[j] = (unsigned)f2bfu(y0) | ((unsigned)f2bfu(y1) << 16);
    }
    return v;
}

// ---------------- MFMA dual GEMM + fused el/er epilogue ----------------
// Y1 = X@WT1^T (=ft), Y2 = X@WT2^T; X staged once. Optional BN+ReLU on X staging.
// T14-lite: ONLY the W2 tile is prefetched to registers before phase-1 MFMA (latency hidden
// under phase-1 compute); X/W1 staging unchanged. Y2 may alias X (row-exclusive blocks).
__global__ __launch_bounds__(256) void gemm_dual(const void* __restrict__ X, int xext,
                                                 const unsigned short* __restrict__ WT1,
                                                 const unsigned short* __restrict__ WT2,
                                                 bf16* __restrict__ Y1, bf16* __restrict__ Y2,
                                                 int nrows, const float* __restrict__ ka,
                                                 const float* __restrict__ kb,
                                                 const void* __restrict__ al,
                                                 const void* __restrict__ ar,
                                                 float* __restrict__ elo,
                                                 float* __restrict__ ero,
                                                 const int* __restrict__ flag) {
    constexpr int LDX = 136;
    __shared__ unsigned short Xs[64 * LDX];   // [r][k]
    __shared__ unsigned short Wt[128 * LDX];  // [c][k], reused for W1 then W2
    int m = (*flag != 0) ? 1 : 0;
    int xfp32 = xext && m;
    int tid = threadIdx.x;
    int rb = blockIdx.x * 64;

    if (xfp32) {
#pragma unroll
        for (int it = 0; it < 8; it++) {  // float4 = 4 elems
            int e = (tid + it * 256) * 4;
            int r = e >> 7, k0 = e & 127;
            int row = rb + r;
            float4 v = {0.f, 0.f, 0.f, 0.f};
            if (row < nrows) v = *(const float4*)((const float*)X + (size_t)row * 128 + k0);
            unsigned lo = (unsigned)f2bfu(v.x) | ((unsigned)f2bfu(v.y) << 16);
            unsigned hi = (unsigned)f2bfu(v.z) | ((unsigned)f2bfu(v.w) << 16);
            uint2 o = {lo, hi};
            *(uint2*)&Xs[r * LDX + k0] = o;
        }
    } else {
#pragma unroll
        for (int it = 0; it < 4; it++) {  // uint4 = 8 bf16
            int e = (tid + it * 256) * 8;
            int r = e >> 7, k0 = e & 127;
            int row = rb + r;
            uint4 v = {0u, 0u, 0u, 0u};
            if (row < nrows) v = *(const uint4*)((const unsigned short*)X + (size_t)row * 128 + k0);
            if (ka) v = bnx8(v, k0, ka, kb);
            *(uint4*)&Xs[r * LDX + k0] = v;
        }
    }
#pragma unroll
    for (int it = 0; it < 8; it++) {  // 128x128 weight tile
        int e = (tid + it * 256) * 8;
        int c = e >> 7, k0 = e & 127;
        *(uint4*)&Wt[c * LDX + k0] = *(const uint4*)(WT1 + (size_t)c * 128 + k0);
    }
    // T14-lite: issue W2 loads now; they stay in flight/registers across phase 1
    uint4 w2v[8];
#pragma unroll
    for (int it = 0; it < 8; it++) {
        int e = (tid + it * 256) * 8;
        int c = e >> 7, k0 = e & 127;
        w2v[it] = *(const uint4*)(WT2 + (size_t)c * 128 + k0);
    }
    __syncthreads();

    int wave = tid >> 6, lane = tid & 63;
    int lr = lane & 15, quad = lane >> 4;
    int mrow = wave * 16 + lr;
    int drow = rb + wave * 16 + quad * 4;

    {
        f32x4 acc[8] = {};
        for (int kk = 0; kk < 128; kk += 32) {
            bf16x8 a = *(const bf16x8*)&Xs[mrow * LDX + kk + quad * 8];
#pragma unroll
            for (int nt = 0; nt < 8; nt++) {
                bf16x8 b = *(const bf16x8*)&Wt[(nt * 16 + lr) * LDX + kk + quad * 8];
                acc[nt] = __builtin_amdgcn_mfma_f32_16x16x32_bf16(a, b, acc[nt], 0, 0, 0);
            }
        }
#pragma unroll
        for (int nt = 0; nt < 8; nt++) {
            int col = nt * 16 + lr;
#pragma unroll
            for (int i = 0; i < 4; i++) {
                int row = drow + i;
                if (row < nrows) Y1[(size_t)row * 128 + col] = __float2bfloat16(acc[nt][i]);
            }
        }
        // ---- fused el/er: el[row,h] = sum_col(head h) ft[row,col]*al_flat[col] ----
        float alv[8], arv[8];
#pragma unroll
        for (int nt = 0; nt < 8; nt++) {
            int c = nt * 16 + lr;
            alv[nt] = ldx(al, c, m);
            arv[nt] = ldx(ar, c, m);
        }
        float eo = 0.f, ro = 0.f;
#pragma unroll
        for (int i = 0; i < 4; i++) {
#pragma unroll
            for (int h = 0; h < 4; h++) {
                float es = acc[2 * h][i] * alv[2 * h] + acc[2 * h + 1][i] * alv[2 * h + 1];
                float rs = acc[2 * h][i] * arv[2 * h] + acc[2 * h + 1][i] * arv[2 * h + 1];
#pragma unroll
                for (int off = 1; off < 16; off <<= 1) {
                    es += __shfl_xor(es, off);
                    rs += __shfl_xor(rs, off);
                }
                bool mine = (lr == i * 4 + h);  // (i,h) -> lane: el idx = drow*4 + lr
                eo = mine ? es : eo;
                ro = mine ? rs : ro;
            }
        }
        int erow = drow + (lr >> 2);
        if (erow < nrows) {
            elo[(size_t)drow * 4 + lr] = eo;  // coalesced 64B per quad
            ero[(size_t)drow * 4 + lr] = ro;
        }
    }
    __syncthreads();  // all waves done reading W1 tile
#pragma unroll
    for (int it = 0; it < 8; it++) {  // registers -> LDS (no global latency here)
        int e = (tid + it * 256) * 8;
        int c = e >> 7, k0 = e & 127;
        *(uint4*)&Wt[c * LDX + k0] = w2v[it];
    }
    __syncthreads();
    {
        f32x4 acc[8] = {};
        for (int kk = 0; kk < 128; kk += 32) {
            bf16x8 a = *(const bf16x8*)&Xs[mrow * LDX + kk + quad * 8];
#pragma unroll
            for (int nt = 0; nt < 8; nt++) {
                bf16x8 b = *(const bf16x8*)&Wt[(nt * 16 + lr) * LDX + kk + quad * 8];
                acc[nt] = __builtin_amdgcn_mfma_f32_16x16x32_bf16(a, b, acc[nt], 0, 0, 0);
            }
        }
#pragma unroll
        for (int nt = 0; nt < 8; nt++) {
            int col = nt * 16 + lr;
#pragma unroll
            for (int i = 0; i < 4; i++) {
                int row = drow + i;
                if (row < nrows) Y2[(size_t)row * 128 + col] = __float2bfloat16(acc[nt][i]);
            }
        }
    }
}

// ---------------- layer-2 fused GEMM: stage BN(hbuf) once ----------------
// WT: [208][128]  rows 0..159 = w_fc2^T, rows 160..207 = wmt (zero-pad >=40)
// writes: Y[.,0:160] = X@w_fc2 ; X[.,0:40] = X@wmt^T (in-place, row-exclusive)
// T14-lite: phase-2 W rows prefetched to registers before phase-1 MFMA.
__global__ __launch_bounds__(256) void gemm_final(bf16* __restrict__ X,
                                                  const unsigned short* __restrict__ WT,
                                                  bf16* __restrict__ Y, int nrows,
                                                  const float* __restrict__ ka,
                                                  const float* __restrict__ kb) {
    constexpr int LDX = 136;
    __shared__ unsigned short Xs[64 * LDX];   // [r][k]
    __shared__ unsigned short Wt[128 * LDX];  // phase1: rows 0..127; phase2: rows 128..207
    int tid = threadIdx.x;
    int rb = blockIdx.x * 64;

#pragma unroll
    for (int it = 0; it < 4; it++) {
        int e = (tid + it * 256) * 8;
        int r = e >> 7, k0 = e & 127;
        int row = rb + r;
        uint4 v = {0u, 0u, 0u, 0u};
        if (row < nrows) v = *(const uint4*)((const unsigned short*)X + (size_t)row * 128 + k0);
        v = bnx8(v, k0, ka, kb);
        *(uint4*)&Xs[r * LDX + k0] = v;
    }
#pragma unroll
    for (int it = 0; it < 8; it++) {
        int e = (tid + it * 256) * 8;
        int c = e >> 7, k0 = e & 127;
        *(uint4*)&Wt[c * LDX + k0] = *(const uint4*)(WT + (size_t)c * 128 + k0);
    }
    uint4 w2v[5];
#pragma unroll
    for (int it = 0; it < 5; it++) {  // 80 rows (128..207), prefetched
        int e = (tid + it * 256) * 8;
        int c = e >> 7, k0 = e & 127;
        w2v[it] = *(const uint4*)(WT + (size_t)(128 + c) * 128 + k0);
    }
    __syncthreads();

    int wave = tid >> 6, lane = tid & 63;
    int lr = lane & 15, quad = lane >> 4;
    int mrow = wave * 16 + lr;
    int drow = rb + wave * 16 + quad * 4;

    {  // phase 1: output cols 0..127
        f32x4 acc[8] = {};
        for (int kk = 0; kk < 128; kk += 32) {
            bf16x8 a = *(const bf16x8*)&Xs[mrow * LDX + kk + quad * 8];
#pragma unroll
            for (int nt = 0; nt < 8; nt++) {
                bf16x8 b = *(const bf16x8*)&Wt[(nt * 16 + lr) * LDX + kk + quad * 8];
                acc[nt] = __builtin_amdgcn_mfma_f32_16x16x32_bf16(a, b, acc[nt], 0, 0, 0);
            }
        }
#pragma unroll
        for (int nt = 0; nt < 8; nt++) {
            int col = nt * 16 + lr;
#pragma unroll
            for (int i = 0; i < 4; i++) {
                int row = drow + i;
                if (row < nrows) Y[(size_t)row * 160 + col] = __float2bfloat16(acc[nt][i]);
            }
        }
    }
    __syncthreads();
#pragma unroll
    for (int it = 0; it < 5; it++) {  // registers -> LDS
        int e = (tid + it * 256) * 8;
        int c = e >> 7, k0 = e & 127;
        *(uint4*)&Wt[c * LDX + k0] = w2v[it];
    }
    __syncthreads();
    {  // phase 2: output cols 128..159 (->Y) and skipmean cols 0..39 (->X)
        f32x4 acc[5] = {};
        for (int kk = 0; kk < 128; kk += 32) {
            bf16x8 a = *(const bf16x8*)&Xs[mrow * LDX + kk + quad * 8];
#pragma unroll
            for (int nt = 0; nt < 5; nt++) {
                bf16x8 b = *(const bf16x8*)&Wt[(nt * 16 + lr) * LDX + kk + quad * 8];
                acc[nt] = __builtin_amdgcn_mfma_f32_16x16x32_bf16(a, b, acc[nt], 0, 0, 0);
            }
        }
#pragma unroll
        for (int nt = 0; nt < 5; nt++) {
            int colg = 128 + nt * 16 + lr;
#pragma unroll
            for (int i = 0; i < 4; i++) {
                int row = drow + i;
                if (row >= nrows) continue;
                if (colg < 160) {
                    Y[(size_t)row * 160 + colg] = __float2bfloat16(acc[nt][i]);
                } else {
                    int sc = colg - 160;
                    if (sc < 40) X[(size_t)row * 128 + sc] = __float2bfloat16(acc[nt][i]);
                }
            }
        }
    }
}

// ---------------- el/er: [N,H] dot over F (layer 2 only, F=40) ----------------
__global__ void elr_kernel(const bf16* __restrict__ ft, const void* __restrict__ al,
                           const void* __restrict__ ar, float* __restrict__ el,
                           float* __restrict__ er, int n, int F, const int* __restrict__ flag) {
    int m = (*flag != 0) ? 1 : 0;
    int gid = blockIdx.x * blockDim.x + threadIdx.x;
    if (gid >= n * 4) return;
    int nid = gid >> 2, h = gid & 3;
    const bf16* f = ft + (size_t)nid * (4 * F) + h * F;
    float sl = 0.f, sr = 0.f;
    for (int i0 = 0; i0 < F; i0 += 8) {
        bf16x8 v8 = *(const bf16x8*)(f + i0);
#pragma unroll
        for (int i = 0; i < 8; i++) {
            float v = __uint_as_float(((unsigned)(unsigned short)v8[i]) << 16);
            sl += v * ldx(al, h * F + i0 + i, m);
            sr += v * ldx(ar, h * F + i0 + i, m);
        }
    }
    el[gid] = sl;
    er[gid] = sr;
}

// ---------------- per-dst softmax + aggregation: ONE WAVE PER NODE, zero barriers ----------------
// Gather: batches of 8 edges; u broadcast via readlane (SGPR base), 8 loads in flight.
template <int FTOT, bool FINAL>
__global__ __launch_bounds__(256) void agg_wave(
    const bf16* __restrict__ ft, const float* __restrict__ el, const float* __restrict__ er,
    const int* __restrict__ indptr, const int* __restrict__ csr_src,
    const void* __restrict__ bias, const void* __restrict__ h_in,
    const bf16* __restrict__ skip_pre, bf16* __restrict__ out,
    const void* __restrict__ bias_last, void* __restrict__ fout,
    const int* __restrict__ flag) {
    constexpr int HF = FTOT / 4;
    int m = (*flag != 0) ? 1 : 0;
    int lane = threadIdx.x & 63;
    int v = blockIdx.x * 4 + (threadIdx.x >> 6);
    if (v >= GN) return;
    int beg = indptr[v], end = indptr[v + 1];
    beg = max(0, min(beg, GE));
    end = max(beg, min(end, GE));

    int h = lane & 3, jl = lane >> 2;  // weight-phase mapping: edge slot jl, head h
    int c0 = 2 * lane;                 // gather-phase feature pair
    int h0 = c0 / HF;
    float erv = er[v * 4 + h];

    float a0 = 0.f, a1 = 0.f, a2 = 0.f, a3 = 0.f;
    float s_part = 0.f;

    for (int cb = beg; cb < end; cb += 16) {
        int chn = end - cb;
        chn = chn < 16 ? chn : 16;
        // ---- weight phase (this chunk's 16 edges) ----
        int u = csr_src[cb + (jl < chn ? jl : chn - 1)];
        u = min(max(u, 0), GN - 1);
        float e = el[u * 4 + h] + erv;
        e = e > 0.f ? e : 0.2f * e;
        float w = (jl < chn) ? __expf(fminf(e, 60.f)) : 0.f;
        s_part += w;
        // ---- gather phase: batches of 8 edges; all loads independent, issued together ----
#pragma unroll
        for (int jb = 0; jb < 16; jb += 8) {
            if (jb >= chn) break;  // wave-uniform
            unsigned pq[8];
            float wqv[8];
            unsigned pbq[8];
#pragma unroll
            for (int q = 0; q < 8; q++) {
                int j4 = (jb + q) * 4;
                int us = __builtin_amdgcn_readlane(u, j4);  // SGPR base, no LDS-pipe dep
                pq[q] = *(const unsigned*)(ft + (size_t)us * FTOT + c0);
                wqv[q] = __shfl(w, j4 + h0);
                if constexpr (FINAL) {
                    if (lane < 16) {
                        pbq[q] = *(const unsigned*)(ft + (size_t)us * FTOT + 128 + c0);
                    }
                }
            }
#pragma unroll
            for (int q = 0; q < 8; q++) {
                a0 += wqv[q] * lo16(pq[q]);
                a1 += wqv[q] * hi16(pq[q]);
                if constexpr (FINAL) {
                    // pair1 cols 128..159 are head 3: uniform weight via readlane
                    float wb = __uint_as_float(
                        __builtin_amdgcn_readlane(__float_as_uint(w), (jb + q) * 4 + 3));
                    if (lane < 16) {
                        a2 += wb * lo16(pbq[q]);
                        a3 += wb * hi16(pbq[q]);
                    }
                }
            }
        }
    }

    // ---- s reduction: butterfly over slot bits (head preserved in lane&3) ----
#pragma unroll
    for (int off = 4; off < 64; off <<= 1) s_part += __shfl_xor(s_part, off);
    float s0 = __shfl(s_part, h0);  // lane h0 (0..3) holds head-h0 total

    float r0 = (s0 > 0.f) ? a0 / s0 : 0.f;
    float r1 = (s0 > 0.f) ? a1 / s0 : 0.f;

    if constexpr (!FINAL) {
        unsigned pk = *(const unsigned*)(skip_pre + (size_t)v * FTOT + c0);
        float o0 = r0 + ldx(bias, c0, m) + lo16(pk);
        float o1 = r1 + ldx(bias, c0 + 1, m) + hi16(pk);
        unsigned po = ((unsigned)f2bfu(guard_finite(o1)) << 16) |
                      (unsigned)f2bfu(guard_finite(o0));
        *(unsigned*)(out + (size_t)v * FTOT + c0) = po;
    } else {
        float s3 = __shfl(s_part, 3);
        float o0 = r0 + ldx(bias, c0, m);
        float o1 = r1 + ldx(bias, c0 + 1, m);
        float r2 = (s3 > 0.f) ? a2 / s3 : 0.f;
        float r3 = (s3 > 0.f) ? a3 / s3 : 0.f;
        int cb0 = 128 + c0;  // meaningful for lane<16 only
        float o2 = r2 + ldx(bias, (cb0 < FTOT) ? cb0 : 0, m);
        float o3 = r3 + ldx(bias, (cb0 + 1 < FTOT) ? cb0 + 1 : 1, m);

        // head-average: lane t<40 needs cols t, t+40, t+80, t+120 (all parity t&1)
        int t = lane;
        bool od = (t & 1);
        int sA = (t >> 1) & 63;
        int sB = ((t + 40) >> 1) & 63;
        int sC = ((t + 80) >> 1) & 63;
        int sD1 = ((t + 120) >> 1) & 63;          // valid when t<8 (col<128, from o0/o1)
        int sD2 = ((t >= 8 ? t - 8 : 0) >> 1);    // valid when t>=8 (col>=128, from o2/o3)
        float vA0 = __shfl(o0, sA), vA1 = __shfl(o1, sA);
        float vB0 = __shfl(o0, sB), vB1 = __shfl(o1, sB);
        float vC0 = __shfl(o0, sC), vC1 = __shfl(o1, sC);
        float vD10 = __shfl(o0, sD1), vD11 = __shfl(o1, sD1);
        float vD20 = __shfl(o2, sD2), vD21 = __shfl(o3, sD2);
        float vA = od ? vA1 : vA0;
        float vB = od ? vB1 : vB0;
        float vC = od ? vC1 : vC0;
        float vD = (t < 8) ? (od ? vD11 : vD10) : (od ? vD21 : vD20);

        float x = -3.0e38f;
        if (t < 40) {
            float sm = __bfloat162float(((const bf16*)h_in)[(size_t)v * 128 + t]);
            x = 0.25f * (vA + vB + vC + vD) + sm + ldx(bias_last, t, m);
        }
        float mx = x;
#pragma unroll
        for (int off = 1; off < 64; off <<= 1) mx = fmaxf(mx, __shfl_xor(mx, off));
        float ex = (t < 40) ? __expf(x - mx) : 0.f;
        float sum = ex;
#pragma unroll
        for (int off = 1; off < 64; off <<= 1) sum += __shfl_xor(sum, off);
        if (t < 40) stx(fout, (size_t)v * 40 + t, m, guard_finite(x - mx - __logf(sum)));
    }
}

// ---------------- BatchNorm stats on bf16 [N,128]: vectorized + LDS reduce ----------------
__global__ void bn_stats(const bf16* __restrict__ x, float* __restrict__ gsum,
                         float* __restrict__ gsq, int n) {
    __shared__ float ls[128], lq[128];
    int tid = threadIdx.x;  // 256
    if (tid < 128) {
        ls[tid] = 0.f;
        lq[tid] = 0.f;
    }
    __syncthreads();
    int rg = tid >> 4;         // 0..15 row substream
    int c8 = (tid & 15) * 8;   // col start
    int rows_per_block = (n + gridDim.x - 1) / gridDim.x;
    int r0 = blockIdx.x * rows_per_block;
    int r1 = min(n, r0 + rows_per_block);
    float s[8] = {}, q[8] = {};
    for (int r = r0 + rg; r < r1; r += 16) {
        uint4 v = *(const uint4*)((const unsigned short*)x + (size_t)r * 128 + c8);
        unsigned* pw = (unsigned*)&v;
#pragma unroll
        for (int i = 0; i < 4; i++) {
            float v0 = lo16(pw[i]), v1 = hi16(pw[i]);
            s[2 * i] += v0;
            q[2 * i] += v0 * v0;
            s[2 * i + 1] += v1;
            q[2 * i + 1] += v1 * v1;
        }
    }
#pragma unroll
    for (int i = 0; i < 8; i++) {
        atomicAdd(&ls[c8 + i], s[i]);
        atomicAdd(&lq[c8 + i], q[i]);
    }
    __syncthreads();
    if (tid < 128) {
        atomicAdd(&gsum[tid], ls[tid]);
        atomicAdd(&gsq[tid], lq[tid]);
    }
}

extern "C" void kernel_launch(void* const* d_in, const int* in_sizes, int n_in,
                              void* d_out, int out_size, void* d_ws, size_t ws_size,
                              hipStream_t stream) {
    const void* feat = d_in[0];
    const int* src = (const int*)d_in[1];
    const int* dst = (const int*)d_in[2];
    const void* w_fc0 = d_in[3];
    const void* al0 = d_in[4];
    const void* ar0 = d_in[5];
    const void* b0 = d_in[6];
    const void* w_lin0 = d_in[7];
    const void* g0 = d_in[8];
    const void* be0 = d_in[9];
    const void* w_fc1 = d_in[10];
    const void* al1 = d_in[11];
    const void* ar1 = d_in[12];
    const void* b1 = d_in[13];
    const void* w_lin1 = d_in[14];
    const void* g1 = d_in[15];
    const void* be1 = d_in[16];
    const void* w_fc2 = d_in[17];
    const void* al2 = d_in[18];
    const void* ar2 = d_in[19];
    const void* b2 = d_in[20];
    const void* w_lin2 = d_in[21];
    const void* bias_last = d_in[22];

    // ---- workspace guard: total need ~34.6 MB ----
    if (ws_size < 35000000) {
        sentinel_kernel<<<(out_size + 255) / 256, 256, 0, stream>>>((unsigned short*)d_out,
                                                                    out_size);
        return;
    }

    char* p = (char*)d_ws;
    auto alloc = [&](size_t bytes) {
        char* r = p;
        p += (bytes + 255) & ~(size_t)255;
        return r;
    };
    bf16* ftb = (bf16*)alloc((size_t)GN * 160 * 2);   // 16.0 MB
    bf16* hbuf = (bf16*)alloc((size_t)GN * 128 * 2);  // 12.8 MB
    float* elb = (float*)alloc((size_t)GN * 4 * 4);   // 0.8 MB
    float* erb = (float*)alloc((size_t)GN * 4 * 4);   // 0.8 MB
    int* indptr = (int*)alloc((size_t)(GN + 1) * 4);
    int* cursor = (int*)alloc((size_t)GN * 4);
    int* bsum = (int*)alloc(256 * 4);                 // block sums for 3-pass scan
    unsigned short* wtf0 = (unsigned short*)alloc(128 * 128 * 2);  // pre-transposed weights
    unsigned short* wtl0 = (unsigned short*)alloc(128 * 128 * 2);
    unsigned short* wtf1 = (unsigned short*)alloc(128 * 128 * 2);
    unsigned short* wtl1 = (unsigned short*)alloc(128 * 128 * 2);
    unsigned short* wtf2 = (unsigned short*)alloc(208 * 128 * 2);  // rows 160..207 = wmt
    float* ka0 = (float*)alloc(128 * 4);
    float* kb0 = (float*)alloc(128 * 4);
    float* ka1 = (float*)alloc(128 * 4);
    float* kb1 = (float*)alloc(128 * 4);
    char* zbase = p;  // ---- zero-initialized region ----
    int* deg = (int*)alloc((size_t)GN * 4);
    int* csr = (int*)alloc((size_t)GE * 4);  // 3.2 MB
    float* gs0 = (float*)alloc(128 * 4);
    float* gq0 = (float*)alloc(128 * 4);
    float* gs1 = (float*)alloc(128 * 4);
    float* gq1 = (float*)alloc(128 * 4);
    int* flag = (int*)alloc(4);
    hipMemsetAsync(zbase, 0, (size_t)(p - zbase), stream);

    detect_kernel<<<1, 256, 0, stream>>>((const unsigned short*)feat, flag);

    // CSR build + weight precompute (independent, early)
    const int NB = (GN + 255) / 256;  // 196 scan blocks
    count_kernel<<<(GE + 255) / 256, 256, 0, stream>>>(dst, deg, GE);
    scan1_kernel<<<NB, 256, 0, stream>>>(deg, cursor, bsum, GN);   // cursor = per-block incl scan
    scan2_kernel<<<1, 256, 0, stream>>>(bsum, NB);                 // bsum = exclusive block offs
    scan3_kernel<<<NB, 256, 0, stream>>>(deg, cursor, bsum, indptr, cursor, GN);
    scatter_kernel<<<(GE + 255) / 256, 256, 0, stream>>>(src, dst, cursor, csr, GE);
    wtrans_all<<<(4 * 16384 + 160 * 128 + 48 * 128 + 255) / 256, 256, 0, stream>>>(
        w_fc0, w_lin0, w_fc1, w_lin1, w_fc2, w_lin2, wtf0, wtl0, wtf1, wtl1, wtf2, flag);

    const int AGGB = (GN + 3) / 4;  // 12500 blocks, 4 waves (nodes) each

    // ----- Layer 0 (fused: ftb = feat@w_fc0, hbuf = feat@w_lin0, el/er epilogue) -----
    gemm_dual<<<782, 256, 0, stream>>>(feat, 1, wtf0, wtl0, ftb, hbuf, GN, nullptr, nullptr,
                                       al0, ar0, elb, erb, flag);
    agg_wave<128, false><<<AGGB, 256, 0, stream>>>(ftb, elb, erb, indptr, csr, b0, nullptr,
                                                   hbuf, hbuf, nullptr, nullptr, flag);
    bn_stats<<<256, 256, 0, stream>>>(hbuf, gs0, gq0, GN);
    bn_coef<<<1, 128, 0, stream>>>(gs0, gq0, g0, be0, ka0, kb0, GN, flag);

    // ----- Layer 1 (fused: BN0+ReLU staging; ftb = h1@w_fc1, hbuf <- h1@w_lin1, el/er) -----
    gemm_dual<<<782, 256, 0, stream>>>(hbuf, 0, wtf1, wtl1, ftb, hbuf, GN, ka0, kb0,
                                       al1, ar1, elb, erb, flag);
    agg_wave<128, false><<<AGGB, 256, 0, stream>>>(ftb, elb, erb, indptr, csr, b1, nullptr,
                                                   hbuf, hbuf, nullptr, nullptr, flag);
    bn_stats<<<256, 256, 0, stream>>>(hbuf, gs1, gq1, GN);
    bn_coef<<<1, 128, 0, stream>>>(gs1, gq1, g1, be1, ka1, kb1, GN, flag);

    // ----- Layer 2 (fused: BN1+ReLU staging; ftb = h2@w_fc2 [160 cols]; hbuf[:,0:40] = skipmean) -----
    gemm_final<<<782, 256, 0, stream>>>(hbuf, wtf2, ftb, GN, ka1, kb1);
    elr_kernel<<<(GN * 4 + 255) / 256, 256, 0, stream>>>(ftb, al2, ar2, elb, erb, GN, 40, flag);
    agg_wave<160, true><<<AGGB, 256, 0, stream>>>(ftb, elb, erb, indptr, csr, b2, hbuf,
                                                  nullptr, nullptr, bias_last, d_out, flag);
}

// Round 12
// 444.510 us; speedup vs baseline: 1.0331x; 1.0331x over previous
//
#include <hip/hip_runtime.h>
#include <hip/hip_bf16.h>

#define GN 50000
#define GE 800000
#define GH 4
#define GFH 32
#define GC 40
#define GIN 128

typedef __hip_bfloat16 bf16;
typedef __attribute__((ext_vector_type(8))) short bf16x8;
typedef __attribute__((ext_vector_type(4))) float f32x4;

// mode m: 0 = tensor stored as bf16, 1 = stored as fp32
static __device__ __forceinline__ float ldx(const void* p, size_t i, int m) {
    if (m) return ((const float*)p)[i];
    return __bfloat162float(((const bf16*)p)[i]);
}
static __device__ __forceinline__ void stx(void* p, size_t i, int m, float v) {
    if (m) ((float*)p)[i] = v;
    else ((bf16*)p)[i] = __float2bfloat16(v);
}
static __device__ __forceinline__ unsigned short f2bfu(float v) {
    union { bf16 b; unsigned short u; } cv;
    cv.b = __float2bfloat16(v);
    return cv.u;
}
static __device__ __forceinline__ float lo16(unsigned u) { return __uint_as_float(u << 16); }
static __device__ __forceinline__ float hi16(unsigned u) { return __uint_as_float(u & 0xFFFF0000u); }
static __device__ __forceinline__ float guard_finite(float v) {
    if (!(v == v) || fabsf(v) > 1e30f) return 0.f;
    return v;
}

// ---------------- dtype probe: fp32 misread as bf16 shows wild exponents ----------------
__global__ void detect_kernel(const unsigned short* __restrict__ f, int* __restrict__ flag) {
    int t = threadIdx.x;  // 256
    unsigned short u = f[t];
    int e = (u >> 7) & 0xFF;
    if (e >= 0x8E) atomicAdd(flag, 1);  // |val| >= 2^15 or inf/nan -> not sane bf16 data
}

__global__ void sentinel_kernel(unsigned short* __restrict__ o, int n) {
    int i = blockIdx.x * blockDim.x + threadIdx.x;
    if (i < n) o[i] = 0x3F80;  // bf16 1.0
}

// ---------------- CSR build (simple path; bucketed variant was not faster) ----------------
__global__ void count_kernel(const int* __restrict__ dst, int* __restrict__ deg, int n) {
    int e = blockIdx.x * blockDim.x + threadIdx.x;
    if (e < n) {
        int d = dst[e];
        if (d >= 0 && d < GN) atomicAdd(&deg[d], 1);
    }
}

// ---- 3-pass device-wide scan (indptr / cursor) ----
__global__ void scan1_kernel(const int* __restrict__ deg, int* __restrict__ tmp,
                             int* __restrict__ bsum, int n) {
    int tid = threadIdx.x;
    int i = blockIdx.x * 256 + tid;
    int v = (i < n) ? deg[i] : 0;
    int lane = tid & 63, wid = tid >> 6;
    int s = v;
#pragma unroll
    for (int off = 1; off < 64; off <<= 1) {
        int u = __shfl_up(s, off);
        if (lane >= off) s += u;
    }
    __shared__ int wsum[4];
    if (lane == 63) wsum[wid] = s;
    __syncthreads();
    int woff = 0;
#pragma unroll
    for (int w = 0; w < 4; w++) woff += (w < wid) ? wsum[w] : 0;
    int incl = s + woff;
    if (i < n) tmp[i] = incl;
    if (tid == 255) bsum[blockIdx.x] = incl;  // block total (zeros padded past n)
}

__global__ void scan2_kernel(int* __restrict__ bsum, int nb) {
    int tid = threadIdx.x;
    int v = (tid < nb) ? bsum[tid] : 0;
    int lane = tid & 63, wid = tid >> 6;
    int s = v;
#pragma unroll
    for (int off = 1; off < 64; off <<= 1) {
        int u = __shfl_up(s, off);
        if (lane >= off) s += u;
    }
    __shared__ int wsum[4];
    if (lane == 63) wsum[wid] = s;
    __syncthreads();
    int woff = 0;
#pragma unroll
    for (int w = 0; w < 4; w++) woff += (w < wid) ? wsum[w] : 0;
    if (tid < nb) bsum[tid] = s + woff - v;  // exclusive
}

__global__ void scan3_kernel(const int* __restrict__ deg, const int* __restrict__ tmp,
                             const int* __restrict__ bsum, int* __restrict__ indptr,
                             int* __restrict__ cursor, int n) {
    int i = blockIdx.x * 256 + threadIdx.x;
    if (i < n) {
        int incl = tmp[i] + bsum[blockIdx.x];
        indptr[i + 1] = incl;
        cursor[i] = incl - deg[i];
        if (i == 0) indptr[0] = 0;
    }
}

__global__ void scatter_kernel(const int* __restrict__ src, const int* __restrict__ dst,
                               int* __restrict__ cursor, int* __restrict__ csr_src, int n) {
    int e = blockIdx.x * blockDim.x + threadIdx.x;
    if (e < n) {
        int d = dst[e];
        if (d < 0 || d >= GN) return;
        int p = atomicAdd(&cursor[d], 1);
        if (p >= 0 && p < GE) csr_src[p] = src[e];
    }
}

// ---------------- all weight transposes + wmean in ONE dispatch ----------------
// WT[c][128] = bf16(W[k][c]); tf2 rows 160..207 = wmt (head-mean of w_lin2, zero-pad >=40)
__global__ void wtrans_all(const void* __restrict__ wf0, const void* __restrict__ wl0,
                           const void* __restrict__ wf1, const void* __restrict__ wl1,
                           const void* __restrict__ wf2, const void* __restrict__ wl2,
                           unsigned short* __restrict__ tf0, unsigned short* __restrict__ tl0,
                           unsigned short* __restrict__ tf1, unsigned short* __restrict__ tl1,
                           unsigned short* __restrict__ tf2, const int* __restrict__ flag) {
    int m = (*flag != 0) ? 1 : 0;
    int idx = blockIdx.x * blockDim.x + threadIdx.x;
    if (idx < 4 * 16384) {
        int which = idx >> 14, local = idx & 16383;
        const void* w = (which == 0) ? wf0 : (which == 1) ? wl0 : (which == 2) ? wf1 : wl1;
        unsigned short* t = (which == 0) ? tf0 : (which == 1) ? tl0 : (which == 2) ? tf1 : tl1;
        int c = local & 127, k = local >> 7;
        t[(size_t)c * 128 + k] = f2bfu(ldx(w, (size_t)k * 128 + c, m));
    } else if (idx < 4 * 16384 + 160 * 128) {
        int local = idx - 4 * 16384;
        int c = local % 160, k = local / 160;
        tf2[(size_t)c * 128 + k] = f2bfu(ldx(wf2, (size_t)k * 160 + c, m));
    } else if (idx < 4 * 16384 + 160 * 128 + 48 * 128) {
        int local = idx - 4 * 16384 - 160 * 128;
        int c = local >> 7, k = local & 127;
        float s = 0.f;
        if (c < 40) {
            s = 0.25f * (ldx(wl2, (size_t)k * 160 + c, m) + ldx(wl2, (size_t)k * 160 + 40 + c, m) +
                         ldx(wl2, (size_t)k * 160 + 80 + c, m) +
                         ldx(wl2, (size_t)k * 160 + 120 + c, m));
        }
        tf2[(size_t)(160 + c) * 128 + k] = f2bfu(s);
    }
}

// ---------------- BN coefficients: y = relu(x*ka[c] + kb[c]) ----------------
__global__ void bn_coef(const float* __restrict__ gsum, const float* __restrict__ gsq,
                        const void* __restrict__ g, const void* __restrict__ be,
                        float* __restrict__ ka, float* __restrict__ kb, int n,
                        const int* __restrict__ flag) {
    int c = threadIdx.x;  // 128
    int m = (*flag != 0) ? 1 : 0;
    float inv_n = 1.f / (float)n;
    float mu = gsum[c] * inv_n;
    float var = gsq[c] * inv_n - mu * mu;
    float k = rsqrtf(fmaxf(var, 0.f) + 1e-5f) * ldx(g, c, m);
    ka[c] = k;
    kb[c] = ldx(be, c, m) - mu * k;
}

// BN+ReLU transform of a uint4 (8 bf16 cols starting at k0)
static __device__ __forceinline__ uint4 bnx8(uint4 v, int k0, const float* __restrict__ ka,
                                             const float* __restrict__ kb) {
    unsigned* pw = (unsigned*)&v;
#pragma unroll
    for (int j = 0; j < 4; j++) {
        int c = k0 + 2 * j;
        float y0 = fmaf(lo16(pw[j]), ka[c], kb[c]);
        float y1 = fmaf(hi16(pw[j]), ka[c + 1], kb[c + 1]);
        y0 = y0 > 0.f ? y0 : 0.f;
        y1 = y1 > 0.f ? y1 : 0.f;
        pw[j] = (unsigned)f2bfu(y0) | ((unsigned)f2bfu(y1) << 16);
    }
    return v;
}

// ---------------- MFMA dual GEMM + fused el/er epilogue ----------------
// Y1 = X@WT1^T (=ft), Y2 = X@WT2^T; X staged once. Optional BN+ReLU on X staging.
// Serial W2 load after phase 1 (register prefetch across __syncthreads regresses:
// the compiler drains vmcnt(0) at every barrier, so prefetch only delays phase 1).
// el/er computed from phase-1 acc (fp32 ft tile): head h = col>>5 (F=32 aligned).
// Y2 may alias X (row-exclusive blocks).
__global__ __launch_bounds__(256) void gemm_dual(const void* __restrict__ X, int xext,
                                                 const unsigned short* __restrict__ WT1,
                                                 const unsigned short* __restrict__ WT2,
                                                 bf16* __restrict__ Y1, bf16* __restrict__ Y2,
                                                 int nrows, const float* __restrict__ ka,
                                                 const float* __restrict__ kb,
                                                 const void* __restrict__ al,
                                                 const void* __restrict__ ar,
                                                 float* __restrict__ elo,
                                                 float* __restrict__ ero,
                                                 const int* __restrict__ flag) {
    constexpr int LDX = 136;
    __shared__ unsigned short Xs[64 * LDX];   // [r][k]
    __shared__ unsigned short Wt[128 * LDX];  // [c][k], reused for W1 then W2
    int m = (*flag != 0) ? 1 : 0;
    int xfp32 = xext && m;
    int tid = threadIdx.x;
    int rb = blockIdx.x * 64;

    if (xfp32) {
#pragma unroll
        for (int it = 0; it < 8; it++) {  // float4 = 4 elems
            int e = (tid + it * 256) * 4;
            int r = e >> 7, k0 = e & 127;
            int row = rb + r;
            float4 v = {0.f, 0.f, 0.f, 0.f};
            if (row < nrows) v = *(const float4*)((const float*)X + (size_t)row * 128 + k0);
            unsigned lo = (unsigned)f2bfu(v.x) | ((unsigned)f2bfu(v.y) << 16);
            unsigned hi = (unsigned)f2bfu(v.z) | ((unsigned)f2bfu(v.w) << 16);
            uint2 o = {lo, hi};
            *(uint2*)&Xs[r * LDX + k0] = o;
        }
    } else {
#pragma unroll
        for (int it = 0; it < 4; it++) {  // uint4 = 8 bf16
            int e = (tid + it * 256) * 8;
            int r = e >> 7, k0 = e & 127;
            int row = rb + r;
            uint4 v = {0u, 0u, 0u, 0u};
            if (row < nrows) v = *(const uint4*)((const unsigned short*)X + (size_t)row * 128 + k0);
            if (ka) v = bnx8(v, k0, ka, kb);
            *(uint4*)&Xs[r * LDX + k0] = v;
        }
    }
#pragma unroll
    for (int it = 0; it < 8; it++) {  // 128x128 weight tile
        int e = (tid + it * 256) * 8;
        int c = e >> 7, k0 = e & 127;
        *(uint4*)&Wt[c * LDX + k0] = *(const uint4*)(WT1 + (size_t)c * 128 + k0);
    }
    __syncthreads();

    int wave = tid >> 6, lane = tid & 63;
    int lr = lane & 15, quad = lane >> 4;
    int mrow = wave * 16 + lr;
    int drow = rb + wave * 16 + quad * 4;

    {
        f32x4 acc[8] = {};
        for (int kk = 0; kk < 128; kk += 32) {
            bf16x8 a = *(const bf16x8*)&Xs[mrow * LDX + kk + quad * 8];
#pragma unroll
            for (int nt = 0; nt < 8; nt++) {
                bf16x8 b = *(const bf16x8*)&Wt[(nt * 16 + lr) * LDX + kk + quad * 8];
                acc[nt] = __builtin_amdgcn_mfma_f32_16x16x32_bf16(a, b, acc[nt], 0, 0, 0);
            }
        }
#pragma unroll
        for (int nt = 0; nt < 8; nt++) {
            int col = nt * 16 + lr;
#pragma unroll
            for (int i = 0; i < 4; i++) {
                int row = drow + i;
                if (row < nrows) Y1[(size_t)row * 128 + col] = __float2bfloat16(acc[nt][i]);
            }
        }
        // ---- fused el/er: el[row,h] = sum_col(head h) ft[row,col]*al_flat[col] ----
        float alv[8], arv[8];
#pragma unroll
        for (int nt = 0; nt < 8; nt++) {
            int c = nt * 16 + lr;
            alv[nt] = ldx(al, c, m);
            arv[nt] = ldx(ar, c, m);
        }
        float eo = 0.f, ro = 0.f;
#pragma unroll
        for (int i = 0; i < 4; i++) {
#pragma unroll
            for (int h = 0; h < 4; h++) {
                float es = acc[2 * h][i] * alv[2 * h] + acc[2 * h + 1][i] * alv[2 * h + 1];
                float rs = acc[2 * h][i] * arv[2 * h] + acc[2 * h + 1][i] * arv[2 * h + 1];
#pragma unroll
                for (int off = 1; off < 16; off <<= 1) {
                    es += __shfl_xor(es, off);
                    rs += __shfl_xor(rs, off);
                }
                bool mine = (lr == i * 4 + h);  // (i,h) -> lane: el idx = drow*4 + lr
                eo = mine ? es : eo;
                ro = mine ? rs : ro;
            }
        }
        int erow = drow + (lr >> 2);
        if (erow < nrows) {
            elo[(size_t)drow * 4 + lr] = eo;  // coalesced 64B per quad
            ero[(size_t)drow * 4 + lr] = ro;
        }
    }
    __syncthreads();  // all waves done reading W1 tile
#pragma unroll
    for (int it = 0; it < 8; it++) {
        int e = (tid + it * 256) * 8;
        int c = e >> 7, k0 = e & 127;
        *(uint4*)&Wt[c * LDX + k0] = *(const uint4*)(WT2 + (size_t)c * 128 + k0);
    }
    __syncthreads();
    {
        f32x4 acc[8] = {};
        for (int kk = 0; kk < 128; kk += 32) {
            bf16x8 a = *(const bf16x8*)&Xs[mrow * LDX + kk + quad * 8];
#pragma unroll
            for (int nt = 0; nt < 8; nt++) {
                bf16x8 b = *(const bf16x8*)&Wt[(nt * 16 + lr) * LDX + kk + quad * 8];
                acc[nt] = __builtin_amdgcn_mfma_f32_16x16x32_bf16(a, b, acc[nt], 0, 0, 0);
            }
        }
#pragma unroll
        for (int nt = 0; nt < 8; nt++) {
            int col = nt * 16 + lr;
#pragma unroll
            for (int i = 0; i < 4; i++) {
                int row = drow + i;
                if (row < nrows) Y2[(size_t)row * 128 + col] = __float2bfloat16(acc[nt][i]);
            }
        }
    }
}

// ---------------- layer-2 fused GEMM: stage BN(hbuf) once ----------------
// WT: [208][128]  rows 0..159 = w_fc2^T, rows 160..207 = wmt (zero-pad >=40)
// writes: Y[.,0:160] = X@w_fc2 ; X[.,0:40] = X@wmt^T (in-place, row-exclusive)
__global__ __launch_bounds__(256) void gemm_final(bf16* __restrict__ X,
                                                  const unsigned short* __restrict__ WT,
                                                  bf16* __restrict__ Y, int nrows,
                                                  const float* __restrict__ ka,
                                                  const float* __restrict__ kb) {
    constexpr int LDX = 136;
    __shared__ unsigned short Xs[64 * LDX];   // [r][k]
    __shared__ unsigned short Wt[128 * LDX];  // phase1: rows 0..127; phase2: rows 128..207
    int tid = threadIdx.x;
    int rb = blockIdx.x * 64;

#pragma unroll
    for (int it = 0; it < 4; it++) {
        int e = (tid + it * 256) * 8;
        int r = e >> 7, k0 = e & 127;
        int row = rb + r;
        uint4 v = {0u, 0u, 0u, 0u};
        if (row < nrows) v = *(const uint4*)((const unsigned short*)X + (size_t)row * 128 + k0);
        v = bnx8(v, k0, ka, kb);
        *(uint4*)&Xs[r * LDX + k0] = v;
    }
#pragma unroll
    for (int it = 0; it < 8; it++) {
        int e = (tid + it * 256) * 8;
        int c = e >> 7, k0 = e & 127;
        *(uint4*)&Wt[c * LDX + k0] = *(const uint4*)(WT + (size_t)c * 128 + k0);
    }
    __syncthreads();

    int wave = tid >> 6, lane = tid & 63;
    int lr = lane & 15, quad = lane >> 4;
    int mrow = wave * 16 + lr;
    int drow = rb + wave * 16 + quad * 4;

    {  // phase 1: output cols 0..127
        f32x4 acc[8] = {};
        for (int kk = 0; kk < 128; kk += 32) {
            bf16x8 a = *(const bf16x8*)&Xs[mrow * LDX + kk + quad * 8];
#pragma unroll
            for (int nt = 0; nt < 8; nt++) {
                bf16x8 b = *(const bf16x8*)&Wt[(nt * 16 + lr) * LDX + kk + quad * 8];
                acc[nt] = __builtin_amdgcn_mfma_f32_16x16x32_bf16(a, b, acc[nt], 0, 0, 0);
            }
        }
#pragma unroll
        for (int nt = 0; nt < 8; nt++) {
            int col = nt * 16 + lr;
#pragma unroll
            for (int i = 0; i < 4; i++) {
                int row = drow + i;
                if (row < nrows) Y[(size_t)row * 160 + col] = __float2bfloat16(acc[nt][i]);
            }
        }
    }
    __syncthreads();
#pragma unroll
    for (int it = 0; it < 5; it++) {  // 80 rows (128..207)
        int e = (tid + it * 256) * 8;
        int c = e >> 7, k0 = e & 127;
        *(uint4*)&Wt[c * LDX + k0] = *(const uint4*)(WT + (size_t)(128 + c) * 128 + k0);
    }
    __syncthreads();
    {  // phase 2: output cols 128..159 (->Y) and skipmean cols 0..39 (->X)
        f32x4 acc[5] = {};
        for (int kk = 0; kk < 128; kk += 32) {
            bf16x8 a = *(const bf16x8*)&Xs[mrow * LDX + kk + quad * 8];
#pragma unroll
            for (int nt = 0; nt < 5; nt++) {
                bf16x8 b = *(const bf16x8*)&Wt[(nt * 16 + lr) * LDX + kk + quad * 8];
                acc[nt] = __builtin_amdgcn_mfma_f32_16x16x32_bf16(a, b, acc[nt], 0, 0, 0);
            }
        }
#pragma unroll
        for (int nt = 0; nt < 5; nt++) {
            int colg = 128 + nt * 16 + lr;
#pragma unroll
            for (int i = 0; i < 4; i++) {
                int row = drow + i;
                if (row >= nrows) continue;
                if (colg < 160) {
                    Y[(size_t)row * 160 + colg] = __float2bfloat16(acc[nt][i]);
                } else {
                    int sc = colg - 160;
                    if (sc < 40) X[(size_t)row * 128 + sc] = __float2bfloat16(acc[nt][i]);
                }
            }
        }
    }
}

// ---------------- el/er: [N,H] dot over F (layer 2 only, F=40) ----------------
__global__ void elr_kernel(const bf16* __restrict__ ft, const void* __restrict__ al,
                           const void* __restrict__ ar, float* __restrict__ el,
                           float* __restrict__ er, int n, int F, const int* __restrict__ flag) {
    int m = (*flag != 0) ? 1 : 0;
    int gid = blockIdx.x * blockDim.x + threadIdx.x;
    if (gid >= n * 4) return;
    int nid = gid >> 2, h = gid & 3;
    const bf16* f = ft + (size_t)nid * (4 * F) + h * F;
    float sl = 0.f, sr = 0.f;
    for (int i0 = 0; i0 < F; i0 += 8) {
        bf16x8 v8 = *(const bf16x8*)(f + i0);
#pragma unroll
        for (int i = 0; i < 8; i++) {
            float v = __uint_as_float(((unsigned)(unsigned short)v8[i]) << 16);
            sl += v * ldx(al, h * F + i0 + i, m);
            sr += v * ldx(ar, h * F + i0 + i, m);
        }
    }
    el[gid] = sl;
    er[gid] = sr;
}

// ---------------- per-dst softmax + aggregation: ONE WAVE PER NODE, zero barriers ----------------
// Gather: batches of 8 edges; u broadcast via readlane (SGPR base), 8 loads in flight.
template <int FTOT, bool FINAL>
__global__ __launch_bounds__(256) void agg_wave(
    const bf16* __restrict__ ft, const float* __restrict__ el, const float* __restrict__ er,
    const int* __restrict__ indptr, const int* __restrict__ csr_src,
    const void* __restrict__ bias, const void* __restrict__ h_in,
    const bf16* __restrict__ skip_pre, bf16* __restrict__ out,
    const void* __restrict__ bias_last, void* __restrict__ fout,
    const int* __restrict__ flag) {
    constexpr int HF = FTOT / 4;
    int m = (*flag != 0) ? 1 : 0;
    int lane = threadIdx.x & 63;
    int v = blockIdx.x * 4 + (threadIdx.x >> 6);
    if (v >= GN) return;
    int beg = indptr[v], end = indptr[v + 1];
    beg = max(0, min(beg, GE));
    end = max(beg, min(end, GE));

    int h = lane & 3, jl = lane >> 2;  // weight-phase mapping: edge slot jl, head h
    int c0 = 2 * lane;                 // gather-phase feature pair
    int h0 = c0 / HF;
    float erv = er[v * 4 + h];

    float a0 = 0.f, a1 = 0.f, a2 = 0.f, a3 = 0.f;
    float s_part = 0.f;

    for (int cb = beg; cb < end; cb += 16) {
        int chn = end - cb;
        chn = chn < 16 ? chn : 16;
        // ---- weight phase (this chunk's 16 edges) ----
        int u = csr_src[cb + (jl < chn ? jl : chn - 1)];
        u = min(max(u, 0), GN - 1);
        float e = el[u * 4 + h] + erv;
        e = e > 0.f ? e : 0.2f * e;
        float w = (jl < chn) ? __expf(fminf(e, 60.f)) : 0.f;
        s_part += w;
        // ---- gather phase: batches of 8 edges; all loads independent, issued together ----
#pragma unroll
        for (int jb = 0; jb < 16; jb += 8) {
            if (jb >= chn) break;  // wave-uniform
            unsigned pq[8];
            float wqv[8];
            unsigned pbq[8];
#pragma unroll
            for (int q = 0; q < 8; q++) {
                int j4 = (jb + q) * 4;
                int us = __builtin_amdgcn_readlane(u, j4);  // SGPR base, no LDS-pipe dep
                pq[q] = *(const unsigned*)(ft + (size_t)us * FTOT + c0);
                wqv[q] = __shfl(w, j4 + h0);
                if constexpr (FINAL) {
                    if (lane < 16) {
                        pbq[q] = *(const unsigned*)(ft + (size_t)us * FTOT + 128 + c0);
                    }
                }
            }
#pragma unroll
            for (int q = 0; q < 8; q++) {
                a0 += wqv[q] * lo16(pq[q]);
                a1 += wqv[q] * hi16(pq[q]);
                if constexpr (FINAL) {
                    // pair1 cols 128..159 are head 3: uniform weight via readlane
                    float wb = __uint_as_float(
                        __builtin_amdgcn_readlane(__float_as_uint(w), (jb + q) * 4 + 3));
                    if (lane < 16) {
                        a2 += wb * lo16(pbq[q]);
                        a3 += wb * hi16(pbq[q]);
                    }
                }
            }
        }
    }

    // ---- s reduction: butterfly over slot bits (head preserved in lane&3) ----
#pragma unroll
    for (int off = 4; off < 64; off <<= 1) s_part += __shfl_xor(s_part, off);
    float s0 = __shfl(s_part, h0);  // lane h0 (0..3) holds head-h0 total

    float r0 = (s0 > 0.f) ? a0 / s0 : 0.f;
    float r1 = (s0 > 0.f) ? a1 / s0 : 0.f;

    if constexpr (!FINAL) {
        unsigned pk = *(const unsigned*)(skip_pre + (size_t)v * FTOT + c0);
        float o0 = r0 + ldx(bias, c0, m) + lo16(pk);
        float o1 = r1 + ldx(bias, c0 + 1, m) + hi16(pk);
        unsigned po = ((unsigned)f2bfu(guard_finite(o1)) << 16) |
                      (unsigned)f2bfu(guard_finite(o0));
        *(unsigned*)(out + (size_t)v * FTOT + c0) = po;
    } else {
        float s3 = __shfl(s_part, 3);
        float o0 = r0 + ldx(bias, c0, m);
        float o1 = r1 + ldx(bias, c0 + 1, m);
        float r2 = (s3 > 0.f) ? a2 / s3 : 0.f;
        float r3 = (s3 > 0.f) ? a3 / s3 : 0.f;
        int cb0 = 128 + c0;  // meaningful for lane<16 only
        float o2 = r2 + ldx(bias, (cb0 < FTOT) ? cb0 : 0, m);
        float o3 = r3 + ldx(bias, (cb0 + 1 < FTOT) ? cb0 + 1 : 1, m);

        // head-average: lane t<40 needs cols t, t+40, t+80, t+120 (all parity t&1)
        int t = lane;
        bool od = (t & 1);
        int sA = (t >> 1) & 63;
        int sB = ((t + 40) >> 1) & 63;
        int sC = ((t + 80) >> 1) & 63;
        int sD1 = ((t + 120) >> 1) & 63;          // valid when t<8 (col<128, from o0/o1)
        int sD2 = ((t >= 8 ? t - 8 : 0) >> 1);    // valid when t>=8 (col>=128, from o2/o3)
        float vA0 = __shfl(o0, sA), vA1 = __shfl(o1, sA);
        float vB0 = __shfl(o0, sB), vB1 = __shfl(o1, sB);
        float vC0 = __shfl(o0, sC), vC1 = __shfl(o1, sC);
        float vD10 = __shfl(o0, sD1), vD11 = __shfl(o1, sD1);
        float vD20 = __shfl(o2, sD2), vD21 = __shfl(o3, sD2);
        float vA = od ? vA1 : vA0;
        float vB = od ? vB1 : vB0;
        float vC = od ? vC1 : vC0;
        float vD = (t < 8) ? (od ? vD11 : vD10) : (od ? vD21 : vD20);

        float x = -3.0e38f;
        if (t < 40) {
            float sm = __bfloat162float(((const bf16*)h_in)[(size_t)v * 128 + t]);
            x = 0.25f * (vA + vB + vC + vD) + sm + ldx(bias_last, t, m);
        }
        float mx = x;
#pragma unroll
        for (int off = 1; off < 64; off <<= 1) mx = fmaxf(mx, __shfl_xor(mx, off));
        float ex = (t < 40) ? __expf(x - mx) : 0.f;
        float sum = ex;
#pragma unroll
        for (int off = 1; off < 64; off <<= 1) sum += __shfl_xor(sum, off);
        if (t < 40) stx(fout, (size_t)v * 40 + t, m, guard_finite(x - mx - __logf(sum)));
    }
}

// ---------------- BatchNorm stats on bf16 [N,128]: vectorized + LDS reduce ----------------
__global__ void bn_stats(const bf16* __restrict__ x, float* __restrict__ gsum,
                         float* __restrict__ gsq, int n) {
    __shared__ float ls[128], lq[128];
    int tid = threadIdx.x;  // 256
    if (tid < 128) {
        ls[tid] = 0.f;
        lq[tid] = 0.f;
    }
    __syncthreads();
    int rg = tid >> 4;         // 0..15 row substream
    int c8 = (tid & 15) * 8;   // col start
    int rows_per_block = (n + gridDim.x - 1) / gridDim.x;
    int r0 = blockIdx.x * rows_per_block;
    int r1 = min(n, r0 + rows_per_block);
    float s[8] = {}, q[8] = {};
    for (int r = r0 + rg; r < r1; r += 16) {
        uint4 v = *(const uint4*)((const unsigned short*)x + (size_t)r * 128 + c8);
        unsigned* pw = (unsigned*)&v;
#pragma unroll
        for (int i = 0; i < 4; i++) {
            float v0 = lo16(pw[i]), v1 = hi16(pw[i]);
            s[2 * i] += v0;
            q[2 * i] += v0 * v0;
            s[2 * i + 1] += v1;
            q[2 * i + 1] += v1 * v1;
        }
    }
#pragma unroll
    for (int i = 0; i < 8; i++) {
        atomicAdd(&ls[c8 + i], s[i]);
        atomicAdd(&lq[c8 + i], q[i]);
    }
    __syncthreads();
    if (tid < 128) {
        atomicAdd(&gsum[tid], ls[tid]);
        atomicAdd(&gsq[tid], lq[tid]);
    }
}

extern "C" void kernel_launch(void* const* d_in, const int* in_sizes, int n_in,
                              void* d_out, int out_size, void* d_ws, size_t ws_size,
                              hipStream_t stream) {
    const void* feat = d_in[0];
    const int* src = (const int*)d_in[1];
    const int* dst = (const int*)d_in[2];
    const void* w_fc0 = d_in[3];
    const void* al0 = d_in[4];
    const void* ar0 = d_in[5];
    const void* b0 = d_in[6];
    const void* w_lin0 = d_in[7];
    const void* g0 = d_in[8];
    const void* be0 = d_in[9];
    const void* w_fc1 = d_in[10];
    const void* al1 = d_in[11];
    const void* ar1 = d_in[12];
    const void* b1 = d_in[13];
    const void* w_lin1 = d_in[14];
    const void* g1 = d_in[15];
    const void* be1 = d_in[16];
    const void* w_fc2 = d_in[17];
    const void* al2 = d_in[18];
    const void* ar2 = d_in[19];
    const void* b2 = d_in[20];
    const void* w_lin2 = d_in[21];
    const void* bias_last = d_in[22];

    // ---- workspace guard: total need ~34.6 MB ----
    if (ws_size < 35000000) {
        sentinel_kernel<<<(out_size + 255) / 256, 256, 0, stream>>>((unsigned short*)d_out,
                                                                    out_size);
        return;
    }

    char* p = (char*)d_ws;
    auto alloc = [&](size_t bytes) {
        char* r = p;
        p += (bytes + 255) & ~(size_t)255;
        return r;
    };
    bf16* ftb = (bf16*)alloc((size_t)GN * 160 * 2);   // 16.0 MB
    bf16* hbuf = (bf16*)alloc((size_t)GN * 128 * 2);  // 12.8 MB
    float* elb = (float*)alloc((size_t)GN * 4 * 4);   // 0.8 MB
    float* erb = (float*)alloc((size_t)GN * 4 * 4);   // 0.8 MB
    int* indptr = (int*)alloc((size_t)(GN + 1) * 4);
    int* cursor = (int*)alloc((size_t)GN * 4);
    int* bsum = (int*)alloc(256 * 4);                 // block sums for 3-pass scan
    unsigned short* wtf0 = (unsigned short*)alloc(128 * 128 * 2);  // pre-transposed weights
    unsigned short* wtl0 = (unsigned short*)alloc(128 * 128 * 2);
    unsigned short* wtf1 = (unsigned short*)alloc(128 * 128 * 2);
    unsigned short* wtl1 = (unsigned short*)alloc(128 * 128 * 2);
    unsigned short* wtf2 = (unsigned short*)alloc(208 * 128 * 2);  // rows 160..207 = wmt
    float* ka0 = (float*)alloc(128 * 4);
    float* kb0 = (float*)alloc(128 * 4);
    float* ka1 = (float*)alloc(128 * 4);
    float* kb1 = (float*)alloc(128 * 4);
    char* zbase = p;  // ---- zero-initialized region ----
    int* deg = (int*)alloc((size_t)GN * 4);
    int* csr = (int*)alloc((size_t)GE * 4);  // 3.2 MB
    float* gs0 = (float*)alloc(128 * 4);
    float* gq0 = (float*)alloc(128 * 4);
    float* gs1 = (float*)alloc(128 * 4);
    float* gq1 = (float*)alloc(128 * 4);
    int* flag = (int*)alloc(4);
    hipMemsetAsync(zbase, 0, (size_t)(p - zbase), stream);

    detect_kernel<<<1, 256, 0, stream>>>((const unsigned short*)feat, flag);

    // CSR build + weight precompute (independent, early)
    const int NB = (GN + 255) / 256;  // 196 scan blocks
    count_kernel<<<(GE + 255) / 256, 256, 0, stream>>>(dst, deg, GE);
    scan1_kernel<<<NB, 256, 0, stream>>>(deg, cursor, bsum, GN);   // cursor = per-block incl scan
    scan2_kernel<<<1, 256, 0, stream>>>(bsum, NB);                 // bsum = exclusive block offs
    scan3_kernel<<<NB, 256, 0, stream>>>(deg, cursor, bsum, indptr, cursor, GN);
    scatter_kernel<<<(GE + 255) / 256, 256, 0, stream>>>(src, dst, cursor, csr, GE);
    wtrans_all<<<(4 * 16384 + 160 * 128 + 48 * 128 + 255) / 256, 256, 0, stream>>>(
        w_fc0, w_lin0, w_fc1, w_lin1, w_fc2, w_lin2, wtf0, wtl0, wtf1, wtl1, wtf2, flag);

    const int AGGB = (GN + 3) / 4;  // 12500 blocks, 4 waves (nodes) each

    // ----- Layer 0 (fused: ftb = feat@w_fc0, hbuf = feat@w_lin0, el/er epilogue) -----
    gemm_dual<<<782, 256, 0, stream>>>(feat, 1, wtf0, wtl0, ftb, hbuf, GN, nullptr, nullptr,
                                       al0, ar0, elb, erb, flag);
    agg_wave<128, false><<<AGGB, 256, 0, stream>>>(ftb, elb, erb, indptr, csr, b0, nullptr,
                                                   hbuf, hbuf, nullptr, nullptr, flag);
    bn_stats<<<256, 256, 0, stream>>>(hbuf, gs0, gq0, GN);
    bn_coef<<<1, 128, 0, stream>>>(gs0, gq0, g0, be0, ka0, kb0, GN, flag);

    // ----- Layer 1 (fused: BN0+ReLU staging; ftb = h1@w_fc1, hbuf <- h1@w_lin1, el/er) -----
    gemm_dual<<<782, 256, 0, stream>>>(hbuf, 0, wtf1, wtl1, ftb, hbuf, GN, ka0, kb0,
                                       al1, ar1, elb, erb, flag);
    agg_wave<128, false><<<AGGB, 256, 0, stream>>>(ftb, elb, erb, indptr, csr, b1, nullptr,
                                                   hbuf, hbuf, nullptr, nullptr, flag);
    bn_stats<<<256, 256, 0, stream>>>(hbuf, gs1, gq1, GN);
    bn_coef<<<1, 128, 0, stream>>>(gs1, gq1, g1, be1, ka1, kb1, GN, flag);

    // ----- Layer 2 (fused: BN1+ReLU staging; ftb = h2@w_fc2 [160 cols]; hbuf[:,0:40] = skipmean) -----
    gemm_final<<<782, 256, 0, stream>>>(hbuf, wtf2, ftb, GN, ka1, kb1);
    elr_kernel<<<(GN * 4 + 255) / 256, 256, 0, stream>>>(ftb, al2, ar2, elb, erb, GN, 40, flag);
    agg_wave<160, true><<<AGGB, 256, 0, stream>>>(ftb, elb, erb, indptr, csr, b2, hbuf,
                                                  nullptr, nullptr, bias_last, d_out, flag);
}